// Round 3
// baseline (87.141 us; speedup 1.0000x reference)
//
#include <hip/hip_runtime.h>

#define BATCH 32
#define SLEN  128
#define EMB   768
#define DIM   1024
#define NW    10

// Fully fused: one block per batch element. mean -> circuit -> e-write -> score -> clip.
// No workspace, no atomics, no inter-kernel handoffs.
__global__ void __launch_bounds__(1024) fused_kernel(
        const float* __restrict__ x, const float* __restrict__ tx,
        const float* __restrict__ ty, float* __restrict__ out, int interleaved) {
    __shared__ float re[DIM], im[DIM];
    __shared__ float cx[NW], sx[NW], cy[NW], sy[NW];
    __shared__ float part[16];
    int b = blockIdx.x, t = threadIdx.x;

    if (t < NW) {
        float a = tx[t]; cx[t] = cosf(a); sx[t] = sinf(a);
        float c = ty[t]; cy[t] = cosf(c); sy[t] = sinf(c);
    }

    // ---- mean over s: re[i] = mean_s x[b,s,i], im = 0 ----
    if (t < EMB) {
        const float* xp = x + (size_t)b * SLEN * EMB + t;
        float s0 = 0.f, s1 = 0.f, s2 = 0.f, s3 = 0.f;
        #pragma unroll 8
        for (int s = 0; s < SLEN; s += 4) {
            s0 += xp[(size_t)(s + 0) * EMB];
            s1 += xp[(size_t)(s + 1) * EMB];
            s2 += xp[(size_t)(s + 2) * EMB];
            s3 += xp[(size_t)(s + 3) * EMB];
        }
        re[t] = (s0 + s1 + s2 + s3) * (1.0f / SLEN);
    } else {
        re[t] = 0.f;
    }
    im[t] = 0.f;
    __syncthreads();

    // ---- circuit: 3 x { RX layer, RY layer, CZ ring } ----
    // Wire k acts on bit p = 9-k (wire 0 = MSB in kron order).
    for (int rep = 0; rep < 3; ++rep) {
        // RX: new0=(c*r0+s*m1)+i(c*m0-s*r1); new1=(c*r1+s*m0)+i(c*m1-s*r0)
        for (int k = 0; k < NW; ++k) {
            if (t < 512) {
                int p = 9 - k;
                int i0 = ((t >> p) << (p + 1)) | (t & ((1 << p) - 1));
                int i1 = i0 | (1 << p);
                float c = cx[k], s = sx[k];
                float r0 = re[i0], m0 = im[i0], r1 = re[i1], m1 = im[i1];
                re[i0] = c * r0 + s * m1;  im[i0] = c * m0 - s * r1;
                re[i1] = c * r1 + s * m0;  im[i1] = c * m1 - s * r0;
            }
            __syncthreads();
        }
        // RY: new0 = c*a0 - s*a1; new1 = s*a0 + c*a1 (componentwise re/im)
        for (int k = 0; k < NW; ++k) {
            if (t < 512) {
                int p = 9 - k;
                int i0 = ((t >> p) << (p + 1)) | (t & ((1 << p) - 1));
                int i1 = i0 | (1 << p);
                float c = cy[k], s = sy[k];
                float r0 = re[i0], m0 = im[i0], r1 = re[i1], m1 = im[i1];
                re[i0] = c * r0 - s * r1;  im[i0] = c * m0 - s * m1;
                re[i1] = s * r0 + c * r1;  im[i1] = s * m0 + c * m1;
            }
            __syncthreads();
        }
        // CZ ring + CZ(0,9): negate where parity of adjacent-AND bits is odd
        {
            int par = __popc((t & (t >> 1)) & 0x1FF) + ((t & (t >> 9)) & 1);
            if (par & 1) { re[t] = -re[t]; im[t] = -im[t]; }
        }
        __syncthreads();
    }

    // ---- write e to output region ----
    float* e_out = out + BATCH;
    if (interleaved) {
        ((float2*)e_out)[b * DIM + t] = make_float2(re[t], im[t]);
    } else {
        e_out[b * DIM + t] = re[t];   // harness astype(float32) keeps only Re(e)
    }

    // ---- score: sum_s ((x_s . u)^2 + (x_s . v)^2) / 128, u=re[0:768], v=im[0:768] ----
    int w = t >> 6, l = t & 63;
    float local = 0.f;
    for (int si = 0; si < 8; ++si) {
        int s = w * 8 + si;
        const float* xr = x + ((size_t)b * SLEN + s) * EMB;
        float du = 0.f, dv = 0.f;
        #pragma unroll
        for (int j = 0; j < 12; ++j) {
            float xv = xr[l + 64 * j];
            du += xv * re[l + 64 * j];
            dv += xv * im[l + 64 * j];
        }
        #pragma unroll
        for (int off = 32; off; off >>= 1) {
            du += __shfl_down(du, off, 64);
            dv += __shfl_down(dv, off, 64);
        }
        if (l == 0) local += du * du + dv * dv;
    }
    if (l == 0) part[w] = local;
    __syncthreads();
    if (t == 0) {
        float a = 0.f;
        #pragma unroll
        for (int i = 0; i < 16; ++i) a += part[i];
        out[b] = fminf(fmaxf(a * (1.0f / SLEN), 0.f), 1.f);
    }
}

extern "C" void kernel_launch(void* const* d_in, const int* in_sizes, int n_in,
                              void* d_out, int out_size, void* d_ws, size_t ws_size,
                              hipStream_t stream) {
    const float* x  = (const float*)d_in[0];
    const float* tx = (const float*)d_in[1];
    const float* ty = (const float*)d_in[2];
    float* out = (float*)d_out;   // [0,32): scores; [32,...): e (layout per out_size)

    int e_elems = out_size - BATCH;
    int interleaved = (e_elems >= BATCH * DIM * 2) ? 1 : 0;

    fused_kernel<<<BATCH, 1024, 0, stream>>>(x, tx, ty, out, interleaved);
}

// Round 4
// 83.449 us; speedup vs baseline: 1.0442x; 1.0442x over previous
//
#include <hip/hip_runtime.h>

#define BATCH 32
#define SLEN  128
#define EMB   768
#define DIM   1024
#define NW    10

// Skew to break 32-way bank conflicts in the bit-field transpose.
__device__ __forceinline__ int skew(int i) { return i + (i >> 5); }

// One block per batch. Register-resident statevector: thread t owns amplitude t.
// Gates on bits 0..4: __shfl_xor (no barrier). Bits 5..9: via LDS transpose that
// swaps bit-fields [0:5)<->[5:10), so they become shuffles too. Per rep:
//   RX(bits0-4) -> T -> RX(bits5-9), RY(bits5-9) -> T^-1 -> RY(bits0-4) -> CZ
// Valid because all RX commute, all RY commute, and RX(w) precedes RY(w) per wire.
__global__ void __launch_bounds__(1024) fused_kernel(
        const float* __restrict__ x, const float* __restrict__ tx,
        const float* __restrict__ ty, float* __restrict__ out, int interleaved) {
    __shared__ float2 st[DIM + DIM / 32];
    __shared__ float cxs[NW], sxs[NW], cys[NW], sys[NW];
    __shared__ float part[16];
    int b = blockIdx.x, t = threadIdx.x;

    if (t < NW) {
        float a = tx[t]; cxs[t] = cosf(a); sxs[t] = sinf(a);
        float c = ty[t]; cys[t] = cosf(c); sys[t] = sinf(c);
    }

    // ---- mean over s directly into registers: r = mean_s x[b,s,t] ----
    float r = 0.f, m = 0.f;
    if (t < EMB) {
        const float* xp = x + (size_t)b * SLEN * EMB + t;
        float s0 = 0.f, s1 = 0.f, s2 = 0.f, s3 = 0.f;
        #pragma unroll 8
        for (int s = 0; s < SLEN; s += 4) {
            s0 += xp[(size_t)(s + 0) * EMB];
            s1 += xp[(size_t)(s + 1) * EMB];
            s2 += xp[(size_t)(s + 2) * EMB];
            s3 += xp[(size_t)(s + 3) * EMB];
        }
        r = (s0 + s1 + s2 + s3) * (1.0f / SLEN);
    }
    __syncthreads();   // angle tables visible

    int tt = ((t & 31) << 5) | (t >> 5);   // bit-field-swapped index

    for (int rep = 0; rep < 3; ++rep) {
        // RX on bits p=0..4 (wires 9..5), original layout. RX symmetric:
        // nr = c*r + s*pm ; nm = c*m - s*pr  (partner = index ^ (1<<p))
        #pragma unroll
        for (int p = 0; p < 5; ++p) {
            float c = cxs[9 - p], s = sxs[9 - p];
            float pr = __shfl_xor(r, 1 << p, 64);
            float pm = __shfl_xor(m, 1 << p, 64);
            float nr = c * r + s * pm, nm = c * m - s * pr;
            r = nr; m = nm;
        }
        // T: now own amplitude tt (its bits 5..9 sit at thread bits 0..4)
        st[skew(t)] = make_float2(r, m);
        __syncthreads();
        { float2 v = st[skew(tt)]; r = v.x; m = v.y; }
        // RX on bits p=5..9 (wires 4..0)
        #pragma unroll
        for (int p = 5; p < 10; ++p) {
            float c = cxs[9 - p], s = sxs[9 - p];
            float pr = __shfl_xor(r, 1 << (p - 5), 64);
            float pm = __shfl_xor(m, 1 << (p - 5), 64);
            float nr = c * r + s * pm, nm = c * m - s * pr;
            r = nr; m = nm;
        }
        // RY on bits p=5..9: nr = c*r + sg*pr, sg = (+s if my bit set else -s)
        #pragma unroll
        for (int p = 5; p < 10; ++p) {
            float c = cys[9 - p], s = sys[9 - p];
            float pr = __shfl_xor(r, 1 << (p - 5), 64);
            float pm = __shfl_xor(m, 1 << (p - 5), 64);
            float sg = ((t >> (p - 5)) & 1) ? s : -s;
            float nr = c * r + sg * pr, nm = c * m + sg * pm;
            r = nr; m = nm;
        }
        // T^-1: back to owning amplitude t
        __syncthreads();
        st[skew(tt)] = make_float2(r, m);
        __syncthreads();
        { float2 v = st[skew(t)]; r = v.x; m = v.y; }
        // RY on bits p=0..4 (wires 9..5)
        #pragma unroll
        for (int p = 0; p < 5; ++p) {
            float c = cys[9 - p], s = sys[9 - p];
            float pr = __shfl_xor(r, 1 << p, 64);
            float pm = __shfl_xor(m, 1 << p, 64);
            float sg = ((t >> p) & 1) ? s : -s;
            float nr = c * r + sg * pr, nm = c * m + sg * pm;
            r = nr; m = nm;
        }
        // CZ ring + CZ(0,9): pointwise sign, no barrier
        int par = __popc((t & (t >> 1)) & 0x1FF) + ((t >> 9) & t & 1);
        if (par & 1) { r = -r; m = -m; }
        __syncthreads();   // protect st before next rep's write / score staging
    }

    // ---- write e ----
    float* e_out = out + BATCH;
    if (interleaved) {
        ((float2*)e_out)[b * DIM + t] = make_float2(r, m);
    } else {
        e_out[b * DIM + t] = r;   // harness astype(float32) keeps only Re(e)
    }

    // ---- stage final e for score, hoist into registers ----
    st[skew(t)] = make_float2(r, m);
    __syncthreads();

    int w = t >> 6, l = t & 63;
    float ur[12], vr[12];
    #pragma unroll
    for (int j = 0; j < 12; ++j) {
        float2 uv = st[skew(l + 64 * j)];
        ur[j] = uv.x; vr[j] = uv.y;
    }

    // score: sum_s ((x_s.u)^2 + (x_s.v)^2) / 128; 16 waves x 8 rows
    float local = 0.f;
    for (int si = 0; si < 8; ++si) {
        int s = w * 8 + si;
        const float* xr = x + ((size_t)b * SLEN + s) * EMB;
        float du = 0.f, dv = 0.f;
        #pragma unroll
        for (int j = 0; j < 12; ++j) {
            float xv = xr[l + 64 * j];
            du += xv * ur[j];
            dv += xv * vr[j];
        }
        #pragma unroll
        for (int off = 32; off; off >>= 1) {
            du += __shfl_down(du, off, 64);
            dv += __shfl_down(dv, off, 64);
        }
        if (l == 0) local += du * du + dv * dv;
    }
    if (l == 0) part[w] = local;
    __syncthreads();
    if (t == 0) {
        float a = 0.f;
        #pragma unroll
        for (int i = 0; i < 16; ++i) a += part[i];
        out[b] = fminf(fmaxf(a * (1.0f / SLEN), 0.f), 1.f);
    }
}

extern "C" void kernel_launch(void* const* d_in, const int* in_sizes, int n_in,
                              void* d_out, int out_size, void* d_ws, size_t ws_size,
                              hipStream_t stream) {
    const float* x  = (const float*)d_in[0];
    const float* tx = (const float*)d_in[1];
    const float* ty = (const float*)d_in[2];
    float* out = (float*)d_out;   // [0,32): scores; [32,...): e (layout per out_size)

    int e_elems = out_size - BATCH;
    int interleaved = (e_elems >= BATCH * DIM * 2) ? 1 : 0;

    fused_kernel<<<BATCH, 1024, 0, stream>>>(x, tx, ty, out, interleaved);
}